// Round 1
// baseline (634.842 us; speedup 1.0000x reference)
//
#include <hip/hip_runtime.h>
#include <hip/hip_bf16.h>

#define NN 50000
#define EE 640000

typedef __attribute__((ext_vector_type(8))) short short8;
typedef __attribute__((ext_vector_type(4))) float f32x4;

__device__ __forceinline__ float bf2f(ushort u) {
    return __uint_as_float(((uint)u) << 16);
}
__device__ __forceinline__ ushort f2bf(float f) {
    uint b = __float_as_uint(f);
    uint r = (b + 0x7fffu + ((b >> 16) & 1u)) >> 16;
    return (ushort)r;
}

// ---- CSR build ------------------------------------------------------------

__global__ __launch_bounds__(256) void k_hist(const int* __restrict__ ei,
                                              int* __restrict__ counts) {
    int e = blockIdx.x * 256 + threadIdx.x;
    if (e < EE) atomicAdd(&counts[ei[EE + e]], 1);
}

__global__ __launch_bounds__(256) void k_scan(const int* __restrict__ counts,
                                              int* __restrict__ offs,
                                              int* __restrict__ cursor) {
    const int t = threadIdx.x;
    const int lane = t & 63, wave = t >> 6;
    const int STRIP = 196;  // 256*196 = 50176 >= 50000
    const int base = t * STRIP;
    int ssum = 0;
    for (int j = 0; j < STRIP; ++j) {
        int idx = base + j;
        if (idx < NN) ssum += counts[idx];
    }
    // wave-inclusive scan
    int x = ssum;
    #pragma unroll
    for (int off = 1; off < 64; off <<= 1) {
        int y = __shfl_up(x, off);
        if (lane >= off) x += y;
    }
    __shared__ int wsum[4];
    if (lane == 63) wsum[wave] = x;
    __syncthreads();
    int woff = 0;
    for (int w = 0; w < wave; ++w) woff += wsum[w];
    int run = woff + x - ssum;  // exclusive prefix of this strip
    for (int j = 0; j < STRIP; ++j) {
        int idx = base + j;
        if (idx < NN) {
            offs[idx] = run;
            cursor[idx] = run;
            run += counts[idx];
        }
    }
    if (t == 255) offs[NN] = run;
}

__global__ __launch_bounds__(256) void k_scatter(const int* __restrict__ ei,
                                                 const float* __restrict__ ea,
                                                 int* __restrict__ cursor,
                                                 uint2* __restrict__ adj) {
    int e = blockIdx.x * 256 + threadIdx.x;
    if (e >= EE) return;
    int d = ei[EE + e];
    int pos = atomicAdd(&cursor[d], 1);
    ushort lo = f2bf(ea[2 * e]);
    ushort hi = f2bf(ea[2 * e + 1]);
    adj[pos] = make_uint2((uint)ei[e], ((uint)hi << 16) | (uint)lo);
}

// ---- Weight composition: WcT[l][t][k] = sum_c Wn[l][k][c] * Wcat[l][c][t] --
// Wcat cols: 0:64 = att_w1[:,0:128,:] (dst part p), 64:128 = att_w1[:,128:256,:]
// (src part q), 128:256 = lin_edge_w[:,0:128,:] (r). Stored transposed for MFMA B.

__global__ __launch_bounds__(256) void k_compose(const float* __restrict__ wn_all,
                                                 const float* __restrict__ aw1,
                                                 const float* __restrict__ wle,
                                                 ushort* __restrict__ wcT) {
    const int l = blockIdx.x >> 7;
    const int k = blockIdx.x & 127;
    const int t = threadIdx.x;  // 0..255 output column
    const float* wn = wn_all + (l * 128 + k) * 128;
    float acc = 0.f;
    for (int c = 0; c < 128; ++c) {
        float cat;
        if (t < 128)
            cat = aw1[(l * 256 + ((t & 64) << 1) + c) * 64 + (t & 63)];
        else
            cat = wle[(l * 130 + c) * 128 + (t - 128)];
        acc += wn[c] * cat;
    }
    wcT[(l * 256 + t) * 128 + k] = f2bf(acc);
}

// ---- K1: pqr = x @ Wc   [N,128]x[128,256] -> bf16 [N,256] -----------------
// One block = 16 rows x 256 cols; 4 waves, each wave 4 16x16 col-tiles.

__global__ __launch_bounds__(256) void k1_gemm(const float* __restrict__ xin,
                                               const ushort* __restrict__ wcT,
                                               ushort* __restrict__ pqr) {
    const int wave = threadIdx.x >> 6;
    const int lane = threadIdx.x & 63;
    const int r0 = blockIdx.x * 16;
    const int c0 = wave * 64;
    const int lrow = lane & 15;
    const int kg = lane >> 4;  // 0..3

    const float* xrow = xin + (r0 + lrow) * 128;
    short8 a[4];
    #pragma unroll
    for (int s = 0; s < 4; ++s) {
        const float* px = xrow + s * 32 + kg * 8;
        float4 u = *(const float4*)(px);
        float4 v = *(const float4*)(px + 4);
        short8 av;
        av[0] = (short)f2bf(u.x); av[1] = (short)f2bf(u.y);
        av[2] = (short)f2bf(u.z); av[3] = (short)f2bf(u.w);
        av[4] = (short)f2bf(v.x); av[5] = (short)f2bf(v.y);
        av[6] = (short)f2bf(v.z); av[7] = (short)f2bf(v.w);
        a[s] = av;
    }

    f32x4 acc[4] = {};
    #pragma unroll
    for (int t = 0; t < 4; ++t) {
        const int col = c0 + t * 16 + lrow;
        #pragma unroll
        for (int s = 0; s < 4; ++s) {
            short8 b = *(const short8*)(wcT + col * 128 + s * 32 + kg * 8);
            acc[t] = __builtin_amdgcn_mfma_f32_16x16x32_bf16(a[s], b, acc[t], 0, 0, 0);
        }
    }
    // D: col = lane&15, row = (lane>>4)*4 + j
    #pragma unroll
    for (int t = 0; t < 4; ++t) {
        const int col = c0 + t * 16 + lrow;
        #pragma unroll
        for (int j = 0; j < 4; ++j) {
            pqr[(r0 + kg * 4 + j) * 256 + col] = f2bf(acc[t][j]);
        }
    }
}

// ---- K2: per-dst aggregation + bias + LN + ReLU + residual ----------------
// One wave per node. Lane i owns att-hidden channel i and out channels 2i,2i+1.

__global__ __launch_bounds__(256) void k2_agg(
    const int* __restrict__ offs, const uint2* __restrict__ adj,
    const ushort* __restrict__ pqr, const float* __restrict__ xin,
    const float* __restrict__ b1v, const float* __restrict__ w2v,
    const float* __restrict__ b2v, const float* __restrict__ web,
    const float* __restrict__ biasv, const float* __restrict__ gammav,
    const float* __restrict__ betav, float* __restrict__ xout, int do_relu) {
    const int lane = threadIdx.x & 63;
    const int n = blockIdx.x * 4 + (threadIdx.x >> 6);

    const float p = bf2f(pqr[n * 256 + lane]);
    const float b1 = b1v[lane];
    const float w2 = w2v[lane];
    const float b2 = b2v[0];
    const int c0 = 2 * lane;
    const float web00 = web[c0], web01 = web[c0 + 1];
    const float web10 = web[128 + c0], web11 = web[128 + c0 + 1];

    float acc0 = 0.f, acc1 = 0.f;
    const int eb = offs[n], ee = offs[n + 1];
    for (int e = eb; e < ee; ++e) {
        const uint2 ad = adj[e];
        const uint src = ad.x;
        const float ea0 = bf2f((ushort)(ad.y & 0xffffu));
        const float ea1 = bf2f((ushort)(ad.y >> 16));
        const float q = bf2f(pqr[src * 256 + 64 + lane]);
        const uint rv = *(const uint*)(pqr + src * 256 + 128 + c0);
        float a1 = fmaxf(p + q + b1, 0.f);
        float s = a1 * w2;
        #pragma unroll
        for (int o = 32; o > 0; o >>= 1) s += __shfl_xor(s, o);
        const float att = 1.f / (1.f + __expf(-(s + b2)));
        const float r0v = bf2f((ushort)(rv & 0xffffu));
        const float r1v = bf2f((ushort)(rv >> 16));
        acc0 += att * (r0v + ea0 * web00 + ea1 * web10);
        acc1 += att * (r1v + ea0 * web01 + ea1 * web11);
    }

    float v0 = acc0 + biasv[c0];
    float v1 = acc1 + biasv[c0 + 1];
    float sm = v0 + v1, sq = v0 * v0 + v1 * v1;
    #pragma unroll
    for (int o = 32; o > 0; o >>= 1) {
        sm += __shfl_xor(sm, o);
        sq += __shfl_xor(sq, o);
    }
    const float mean = sm * (1.f / 128.f);
    const float var = sq * (1.f / 128.f) - mean * mean;
    const float inv = rsqrtf(var + 1e-5f);
    float y0 = (v0 - mean) * inv * gammav[c0] + betav[c0];
    float y1 = (v1 - mean) * inv * gammav[c0 + 1] + betav[c0 + 1];
    if (do_relu) { y0 = fmaxf(y0, 0.f); y1 = fmaxf(y1, 0.f); }
    const float2 xr = *(const float2*)(xin + n * 128 + c0);
    y0 += xr.x;
    y1 += xr.y;
    float2 o2; o2.x = y0; o2.y = y1;
    *(float2*)(xout + n * 128 + c0) = o2;
}

// ---------------------------------------------------------------------------

extern "C" void kernel_launch(void* const* d_in, const int* in_sizes, int n_in,
                              void* d_out, int out_size, void* d_ws, size_t ws_size,
                              hipStream_t stream) {
    const float* x   = (const float*)d_in[0];
    const int*   ei  = (const int*)d_in[1];
    const float* ea  = (const float*)d_in[2];
    const float* wn  = (const float*)d_in[3];
    const float* wle = (const float*)d_in[4];
    const float* aw1 = (const float*)d_in[5];
    const float* ab1 = (const float*)d_in[6];
    const float* aw2 = (const float*)d_in[7];
    const float* ab2 = (const float*)d_in[8];
    const float* bia = (const float*)d_in[9];
    const float* gam = (const float*)d_in[10];
    const float* bet = (const float*)d_in[11];

    char* w = (char*)d_ws;
    size_t o = 0;
    auto alloc = [&](size_t bytes) {
        char* p = w + o;
        o = (o + bytes + 255) & ~(size_t)255;
        return p;
    };
    int*    counts = (int*)alloc((size_t)NN * 4);
    int*    offs   = (int*)alloc((size_t)(NN + 1) * 4);
    int*    cursor = (int*)alloc((size_t)NN * 4);
    uint2*  adj    = (uint2*)alloc((size_t)EE * 8);
    ushort* wcT    = (ushort*)alloc((size_t)3 * 256 * 128 * 2);
    ushort* pqr    = (ushort*)alloc((size_t)NN * 256 * 2);
    float*  xb1    = (float*)alloc((size_t)NN * 128 * 4);
    float*  xb2    = (float*)alloc((size_t)NN * 128 * 4);

    hipMemsetAsync(counts, 0, (size_t)NN * 4, stream);
    k_hist<<<(EE + 255) / 256, 256, 0, stream>>>(ei, counts);
    k_scan<<<1, 256, 0, stream>>>(counts, offs, cursor);
    k_scatter<<<(EE + 255) / 256, 256, 0, stream>>>(ei, ea, cursor, adj);
    k_compose<<<384, 256, 0, stream>>>(wn, aw1, wle, wcT);

    const float* xi = x;
    float* xo = xb1;
    for (int l = 0; l < 3; ++l) {
        k1_gemm<<<NN / 16, 256, 0, stream>>>(xi, wcT + (size_t)l * 256 * 128, pqr);
        const bool last = (l == 2);
        float* out_ptr = last ? (float*)d_out : xo;
        k2_agg<<<NN / 4, 256, 0, stream>>>(
            offs, adj, pqr, xi,
            ab1 + l * 64, aw2 + l * 64, ab2 + l,
            wle + ((size_t)l * 130 + 128) * 128,
            bia + l * 128, gam + l * 128, bet + l * 128,
            out_ptr, last ? 0 : 1);
        xi = out_ptr;
        xo = (l == 0) ? xb2 : xb1;
    }
}

// Round 2
// 507.968 us; speedup vs baseline: 1.2498x; 1.2498x over previous
//
#include <hip/hip_runtime.h>
#include <hip/hip_bf16.h>

#define NN 50000
#define EE 640000
#define NB 196  // ceil(NN/256)

typedef __attribute__((ext_vector_type(8))) short short8;
typedef __attribute__((ext_vector_type(4))) float f32x4;

__device__ __forceinline__ float bf2f(ushort u) {
    return __uint_as_float(((uint)u) << 16);
}
__device__ __forceinline__ ushort f2bf(float f) {
    uint b = __float_as_uint(f);
    uint r = (b + 0x7fffu + ((b >> 16) & 1u)) >> 16;
    return (ushort)r;
}

// ---- CSR build ------------------------------------------------------------

__global__ __launch_bounds__(256) void k_hist(const int* __restrict__ ei,
                                              int* __restrict__ counts) {
    int e = blockIdx.x * 256 + threadIdx.x;
    if (e < EE) atomicAdd(&counts[ei[EE + e]], 1);
}

// 3-phase parallel exclusive scan of counts[NN] -> offs/cursor.

__global__ __launch_bounds__(256) void k_scan_a(const int* __restrict__ counts,
                                                int* __restrict__ bsum) {
    int i = blockIdx.x * 256 + threadIdx.x;
    int v = (i < NN) ? counts[i] : 0;
    #pragma unroll
    for (int o = 32; o > 0; o >>= 1) v += __shfl_xor(v, o);
    __shared__ int ws[4];
    if ((threadIdx.x & 63) == 0) ws[threadIdx.x >> 6] = v;
    __syncthreads();
    if (threadIdx.x == 0) bsum[blockIdx.x] = ws[0] + ws[1] + ws[2] + ws[3];
}

__global__ __launch_bounds__(256) void k_scan_b(const int* __restrict__ bsum,
                                                int* __restrict__ boff,
                                                int* __restrict__ offs) {
    const int t = threadIdx.x;
    const int lane = t & 63, wave = t >> 6;
    int v = (t < NB) ? bsum[t] : 0;
    int x = v;
    #pragma unroll
    for (int o = 1; o < 64; o <<= 1) {
        int y = __shfl_up(x, o);
        if (lane >= o) x += y;
    }
    __shared__ int ws[4];
    if (lane == 63) ws[wave] = x;
    __syncthreads();
    int add = 0;
    for (int w = 0; w < wave; ++w) add += ws[w];
    x += add;                       // inclusive over all 256
    if (t < NB) boff[t] = x - v;    // exclusive
    if (t == 255) offs[NN] = x;     // grand total
}

__global__ __launch_bounds__(256) void k_scan_c(const int* __restrict__ counts,
                                                const int* __restrict__ boff,
                                                int* __restrict__ offs,
                                                int* __restrict__ cursor) {
    int i = blockIdx.x * 256 + threadIdx.x;
    const int lane = threadIdx.x & 63, wave = threadIdx.x >> 6;
    int v = (i < NN) ? counts[i] : 0;
    int x = v;
    #pragma unroll
    for (int o = 1; o < 64; o <<= 1) {
        int y = __shfl_up(x, o);
        if (lane >= o) x += y;
    }
    __shared__ int ws[4];
    if (lane == 63) ws[wave] = x;
    __syncthreads();
    int add = boff[blockIdx.x];
    for (int w = 0; w < wave; ++w) add += ws[w];
    int ex = add + x - v;  // exclusive prefix
    if (i < NN) {
        offs[i] = ex;
        cursor[i] = ex;
    }
}

__global__ __launch_bounds__(256) void k_scatter(const int* __restrict__ ei,
                                                 const float* __restrict__ ea,
                                                 int* __restrict__ cursor,
                                                 uint2* __restrict__ adj) {
    int e = blockIdx.x * 256 + threadIdx.x;
    if (e >= EE) return;
    int d = ei[EE + e];
    int pos = atomicAdd(&cursor[d], 1);
    ushort lo = f2bf(ea[2 * e]);
    ushort hi = f2bf(ea[2 * e + 1]);
    adj[pos] = make_uint2((uint)ei[e], ((uint)hi << 16) | (uint)lo);
}

// ---- Weight composition: WcT[l][t][k] = sum_c Wn[l][k][c] * Wcat[l][c][t] --
// Wcat cols: 0:64 = att_w1[:,0:128,:] (dst part p), 64:128 = att_w1[:,128:256,:]
// (src part q), 128:256 = lin_edge_w[:,0:128,:] (r). Stored transposed for MFMA B.

__global__ __launch_bounds__(256) void k_compose(const float* __restrict__ wn_all,
                                                 const float* __restrict__ aw1,
                                                 const float* __restrict__ wle,
                                                 ushort* __restrict__ wcT) {
    const int l = blockIdx.x >> 7;
    const int k = blockIdx.x & 127;
    const int t = threadIdx.x;  // 0..255 output column
    const float* wn = wn_all + (l * 128 + k) * 128;
    float acc = 0.f;
    for (int c = 0; c < 128; ++c) {
        float cat;
        if (t < 128)
            cat = aw1[(l * 256 + ((t & 64) << 1) + c) * 64 + (t & 63)];
        else
            cat = wle[(l * 130 + c) * 128 + (t - 128)];
        acc += wn[c] * cat;
    }
    wcT[(l * 256 + t) * 128 + k] = f2bf(acc);
}

// ---- K1: pqr = x @ Wc   [N,128]x[128,256] -> bf16 [N,256] -----------------

__global__ __launch_bounds__(256) void k1_gemm(const float* __restrict__ xin,
                                               const ushort* __restrict__ wcT,
                                               ushort* __restrict__ pqr) {
    const int wave = threadIdx.x >> 6;
    const int lane = threadIdx.x & 63;
    const int r0 = blockIdx.x * 16;
    const int c0 = wave * 64;
    const int lrow = lane & 15;
    const int kg = lane >> 4;  // 0..3

    const float* xrow = xin + (r0 + lrow) * 128;
    short8 a[4];
    #pragma unroll
    for (int s = 0; s < 4; ++s) {
        const float* px = xrow + s * 32 + kg * 8;
        float4 u = *(const float4*)(px);
        float4 v = *(const float4*)(px + 4);
        short8 av;
        av[0] = (short)f2bf(u.x); av[1] = (short)f2bf(u.y);
        av[2] = (short)f2bf(u.z); av[3] = (short)f2bf(u.w);
        av[4] = (short)f2bf(v.x); av[5] = (short)f2bf(v.y);
        av[6] = (short)f2bf(v.z); av[7] = (short)f2bf(v.w);
        a[s] = av;
    }

    f32x4 acc[4] = {};
    #pragma unroll
    for (int t = 0; t < 4; ++t) {
        const int col = c0 + t * 16 + lrow;
        #pragma unroll
        for (int s = 0; s < 4; ++s) {
            short8 b = *(const short8*)(wcT + col * 128 + s * 32 + kg * 8);
            acc[t] = __builtin_amdgcn_mfma_f32_16x16x32_bf16(a[s], b, acc[t], 0, 0, 0);
        }
    }
    // D: col = lane&15, row = (lane>>4)*4 + j
    #pragma unroll
    for (int t = 0; t < 4; ++t) {
        const int col = c0 + t * 16 + lrow;
        #pragma unroll
        for (int j = 0; j < 4; ++j) {
            pqr[(r0 + kg * 4 + j) * 256 + col] = f2bf(acc[t][j]);
        }
    }
}

// ---- K2: per-dst aggregation + bias + LN + ReLU + residual ----------------

__global__ __launch_bounds__(256) void k2_agg(
    const int* __restrict__ offs, const uint2* __restrict__ adj,
    const ushort* __restrict__ pqr, const float* __restrict__ xin,
    const float* __restrict__ b1v, const float* __restrict__ w2v,
    const float* __restrict__ b2v, const float* __restrict__ web,
    const float* __restrict__ biasv, const float* __restrict__ gammav,
    const float* __restrict__ betav, float* __restrict__ xout, int do_relu) {
    const int lane = threadIdx.x & 63;
    const int n = blockIdx.x * 4 + (threadIdx.x >> 6);

    const float p = bf2f(pqr[n * 256 + lane]);
    const float b1 = b1v[lane];
    const float w2 = w2v[lane];
    const float b2 = b2v[0];
    const int c0 = 2 * lane;
    const float web00 = web[c0], web01 = web[c0 + 1];
    const float web10 = web[128 + c0], web11 = web[128 + c0 + 1];

    float acc0 = 0.f, acc1 = 0.f;
    const int eb = offs[n], ee = offs[n + 1];
    for (int e = eb; e < ee; ++e) {
        const uint2 ad = adj[e];
        const uint src = ad.x;
        const float ea0 = bf2f((ushort)(ad.y & 0xffffu));
        const float ea1 = bf2f((ushort)(ad.y >> 16));
        const float q = bf2f(pqr[src * 256 + 64 + lane]);
        const uint rv = *(const uint*)(pqr + src * 256 + 128 + c0);
        float a1 = fmaxf(p + q + b1, 0.f);
        float s = a1 * w2;
        #pragma unroll
        for (int o = 32; o > 0; o >>= 1) s += __shfl_xor(s, o);
        const float att = 1.f / (1.f + __expf(-(s + b2)));
        const float r0v = bf2f((ushort)(rv & 0xffffu));
        const float r1v = bf2f((ushort)(rv >> 16));
        acc0 += att * (r0v + ea0 * web00 + ea1 * web10);
        acc1 += att * (r1v + ea0 * web01 + ea1 * web11);
    }

    float v0 = acc0 + biasv[c0];
    float v1 = acc1 + biasv[c0 + 1];
    float sm = v0 + v1, sq = v0 * v0 + v1 * v1;
    #pragma unroll
    for (int o = 32; o > 0; o >>= 1) {
        sm += __shfl_xor(sm, o);
        sq += __shfl_xor(sq, o);
    }
    const float mean = sm * (1.f / 128.f);
    const float var = sq * (1.f / 128.f) - mean * mean;
    const float inv = rsqrtf(var + 1e-5f);
    float y0 = (v0 - mean) * inv * gammav[c0] + betav[c0];
    float y1 = (v1 - mean) * inv * gammav[c0 + 1] + betav[c0 + 1];
    if (do_relu) { y0 = fmaxf(y0, 0.f); y1 = fmaxf(y1, 0.f); }
    const float2 xr = *(const float2*)(xin + n * 128 + c0);
    y0 += xr.x;
    y1 += xr.y;
    float2 o2; o2.x = y0; o2.y = y1;
    *(float2*)(xout + n * 128 + c0) = o2;
}

// ---------------------------------------------------------------------------

extern "C" void kernel_launch(void* const* d_in, const int* in_sizes, int n_in,
                              void* d_out, int out_size, void* d_ws, size_t ws_size,
                              hipStream_t stream) {
    const float* x   = (const float*)d_in[0];
    const int*   ei  = (const int*)d_in[1];
    const float* ea  = (const float*)d_in[2];
    const float* wn  = (const float*)d_in[3];
    const float* wle = (const float*)d_in[4];
    const float* aw1 = (const float*)d_in[5];
    const float* ab1 = (const float*)d_in[6];
    const float* aw2 = (const float*)d_in[7];
    const float* ab2 = (const float*)d_in[8];
    const float* bia = (const float*)d_in[9];
    const float* gam = (const float*)d_in[10];
    const float* bet = (const float*)d_in[11];

    char* w = (char*)d_ws;
    size_t o = 0;
    auto alloc = [&](size_t bytes) {
        char* p = w + o;
        o = (o + bytes + 255) & ~(size_t)255;
        return p;
    };
    int*    counts = (int*)alloc((size_t)NN * 4);
    int*    offs   = (int*)alloc((size_t)(NN + 1) * 4);
    int*    cursor = (int*)alloc((size_t)NN * 4);
    int*    bsum   = (int*)alloc((size_t)NB * 4);
    int*    boff   = (int*)alloc((size_t)NB * 4);
    uint2*  adj    = (uint2*)alloc((size_t)EE * 8);
    ushort* wcT    = (ushort*)alloc((size_t)3 * 256 * 128 * 2);
    ushort* pqr    = (ushort*)alloc((size_t)NN * 256 * 2);
    float*  xb1    = (float*)alloc((size_t)NN * 128 * 4);
    float*  xb2    = (float*)alloc((size_t)NN * 128 * 4);

    hipMemsetAsync(counts, 0, (size_t)NN * 4, stream);
    k_hist<<<(EE + 255) / 256, 256, 0, stream>>>(ei, counts);
    k_scan_a<<<NB, 256, 0, stream>>>(counts, bsum);
    k_scan_b<<<1, 256, 0, stream>>>(bsum, boff, offs);
    k_scan_c<<<NB, 256, 0, stream>>>(counts, boff, offs, cursor);
    k_scatter<<<(EE + 255) / 256, 256, 0, stream>>>(ei, ea, cursor, adj);
    k_compose<<<384, 256, 0, stream>>>(wn, aw1, wle, wcT);

    const float* xi = x;
    float* xo = xb1;
    for (int l = 0; l < 3; ++l) {
        k1_gemm<<<NN / 16, 256, 0, stream>>>(xi, wcT + (size_t)l * 256 * 128, pqr);
        const bool last = (l == 2);
        float* out_ptr = last ? (float*)d_out : xo;
        k2_agg<<<NN / 4, 256, 0, stream>>>(
            offs, adj, pqr, xi,
            ab1 + l * 64, aw2 + l * 64, ab2 + l,
            wle + ((size_t)l * 130 + 128) * 128,
            bia + l * 128, gam + l * 128, bet + l * 128,
            out_ptr, last ? 0 : 1);
        xi = out_ptr;
        xo = (l == 0) ? xb2 : xb1;
    }
}

// Round 3
// 448.459 us; speedup vs baseline: 1.4156x; 1.1327x over previous
//
#include <hip/hip_runtime.h>
#include <hip/hip_bf16.h>

#define NN 50000
#define EE 640000
#define NB 196  // ceil(NN/256)

typedef __attribute__((ext_vector_type(8))) short short8;
typedef __attribute__((ext_vector_type(4))) float f32x4;

__device__ __forceinline__ float bf2f(ushort u) {
    return __uint_as_float(((uint)u) << 16);
}
__device__ __forceinline__ ushort f2bf(float f) {
    uint b = __float_as_uint(f);
    uint r = (b + 0x7fffu + ((b >> 16) & 1u)) >> 16;
    return (ushort)r;
}
__device__ __forceinline__ ushort f2bf_rn(float f) {  // cheap round-to-nearest
    return (ushort)((__float_as_uint(f) + 0x8000u) >> 16);
}

// ---- CSR build ------------------------------------------------------------

__global__ __launch_bounds__(256) void k_hist(const int* __restrict__ ei,
                                              int* __restrict__ counts) {
    int e = blockIdx.x * 256 + threadIdx.x;
    if (e < EE) atomicAdd(&counts[ei[EE + e]], 1);
}

__global__ __launch_bounds__(256) void k_scan_a(const int* __restrict__ counts,
                                                int* __restrict__ bsum) {
    int i = blockIdx.x * 256 + threadIdx.x;
    int v = (i < NN) ? counts[i] : 0;
    #pragma unroll
    for (int o = 32; o > 0; o >>= 1) v += __shfl_xor(v, o);
    __shared__ int ws[4];
    if ((threadIdx.x & 63) == 0) ws[threadIdx.x >> 6] = v;
    __syncthreads();
    if (threadIdx.x == 0) bsum[blockIdx.x] = ws[0] + ws[1] + ws[2] + ws[3];
}

__global__ __launch_bounds__(256) void k_scan_b(const int* __restrict__ bsum,
                                                int* __restrict__ boff,
                                                int* __restrict__ offs) {
    const int t = threadIdx.x;
    const int lane = t & 63, wave = t >> 6;
    int v = (t < NB) ? bsum[t] : 0;
    int x = v;
    #pragma unroll
    for (int o = 1; o < 64; o <<= 1) {
        int y = __shfl_up(x, o);
        if (lane >= o) x += y;
    }
    __shared__ int ws[4];
    if (lane == 63) ws[wave] = x;
    __syncthreads();
    int add = 0;
    for (int w = 0; w < wave; ++w) add += ws[w];
    x += add;
    if (t < NB) boff[t] = x - v;
    if (t == 255) offs[NN] = x;
}

__global__ __launch_bounds__(256) void k_scan_c(const int* __restrict__ counts,
                                                const int* __restrict__ boff,
                                                int* __restrict__ offs,
                                                int* __restrict__ cursor) {
    int i = blockIdx.x * 256 + threadIdx.x;
    const int lane = threadIdx.x & 63, wave = threadIdx.x >> 6;
    int v = (i < NN) ? counts[i] : 0;
    int x = v;
    #pragma unroll
    for (int o = 1; o < 64; o <<= 1) {
        int y = __shfl_up(x, o);
        if (lane >= o) x += y;
    }
    __shared__ int ws[4];
    if (lane == 63) ws[wave] = x;
    __syncthreads();
    int add = boff[blockIdx.x];
    for (int w = 0; w < wave; ++w) add += ws[w];
    int ex = add + x - v;
    if (i < NN) {
        offs[i] = ex;
        cursor[i] = ex;
    }
}

__global__ __launch_bounds__(256) void k_scatter(const int* __restrict__ ei,
                                                 const float* __restrict__ ea,
                                                 int* __restrict__ cursor,
                                                 uint2* __restrict__ adj,
                                                 uint* __restrict__ adst) {
    int e = blockIdx.x * 256 + threadIdx.x;
    if (e >= EE) return;
    int d = ei[EE + e];
    int pos = atomicAdd(&cursor[d], 1);
    ushort lo = f2bf(ea[2 * e]);
    ushort hi = f2bf(ea[2 * e + 1]);
    adj[pos] = make_uint2((uint)ei[e], ((uint)hi << 16) | (uint)lo);
    adst[pos] = (uint)d;
}

// ---- Weight composition ---------------------------------------------------

__global__ __launch_bounds__(256) void k_compose(const float* __restrict__ wn_all,
                                                 const float* __restrict__ aw1,
                                                 const float* __restrict__ wle,
                                                 ushort* __restrict__ wcT) {
    const int l = blockIdx.x >> 7;
    const int k = blockIdx.x & 127;
    const int t = threadIdx.x;
    const float* wn = wn_all + (l * 128 + k) * 128;
    float acc = 0.f;
    for (int c = 0; c < 128; ++c) {
        float cat;
        if (t < 128)
            cat = aw1[(l * 256 + ((t & 64) << 1) + c) * 64 + (t & 63)];
        else
            cat = wle[(l * 130 + c) * 128 + (t - 128)];
        acc += wn[c] * cat;
    }
    wcT[(l * 256 + t) * 128 + k] = f2bf(acc);
}

// ---- K1: pqr = x @ Wc   [N,128]x[128,256] -> bf16 [N,256] -----------------

__global__ __launch_bounds__(256) void k1_gemm(const float* __restrict__ xin,
                                               const ushort* __restrict__ wcT,
                                               ushort* __restrict__ pqr) {
    const int wave = threadIdx.x >> 6;
    const int lane = threadIdx.x & 63;
    const int r0 = blockIdx.x * 16;
    const int c0 = wave * 64;
    const int lrow = lane & 15;
    const int kg = lane >> 4;

    const float* xrow = xin + (r0 + lrow) * 128;
    short8 a[4];
    #pragma unroll
    for (int s = 0; s < 4; ++s) {
        const float* px = xrow + s * 32 + kg * 8;
        float4 u = *(const float4*)(px);
        float4 v = *(const float4*)(px + 4);
        short8 av;
        av[0] = (short)f2bf(u.x); av[1] = (short)f2bf(u.y);
        av[2] = (short)f2bf(u.z); av[3] = (short)f2bf(u.w);
        av[4] = (short)f2bf(v.x); av[5] = (short)f2bf(v.y);
        av[6] = (short)f2bf(v.z); av[7] = (short)f2bf(v.w);
        a[s] = av;
    }

    f32x4 acc[4] = {};
    #pragma unroll
    for (int t = 0; t < 4; ++t) {
        const int col = c0 + t * 16 + lrow;
        #pragma unroll
        for (int s = 0; s < 4; ++s) {
            short8 b = *(const short8*)(wcT + col * 128 + s * 32 + kg * 8);
            acc[t] = __builtin_amdgcn_mfma_f32_16x16x32_bf16(a[s], b, acc[t], 0, 0, 0);
        }
    }
    #pragma unroll
    for (int t = 0; t < 4; ++t) {
        const int col = c0 + t * 16 + lrow;
        #pragma unroll
        for (int j = 0; j < 4; ++j) {
            pqr[(r0 + kg * 4 + j) * 256 + col] = f2bf(acc[t][j]);
        }
    }
}

// ---- K_att: edge-parallel attention scores via MFMA -----------------------
// One wave = 16 edges. A[row=edge][k=hidden ch] = relu(p[dst]+q[src]+b1),
// B col0 = w2, others 0. C[edge][0] = score. No cross-lane ops.

__global__ __launch_bounds__(256) void k_att(const uint2* __restrict__ adj,
                                             const uint* __restrict__ adst,
                                             const ushort* __restrict__ pqr,
                                             const float* __restrict__ b1v,
                                             const float* __restrict__ w2v,
                                             const float* __restrict__ b2v,
                                             float* __restrict__ attv) {
    const int lane = threadIdx.x & 63;
    const int e0 = blockIdx.x * 64 + (threadIdx.x >> 6) * 16;
    const int row = lane & 15;  // local edge
    const int kg = lane >> 4;   // k-group 0..3
    const int eidx = e0 + row;
    const uint src = adj[eidx].x;
    const uint dst = adst[eidx];
    const float b2 = b2v[0];

    // B fragment: lane holds B[k=kg*8+j][col=row]; col 0 = w2, rest 0.
    short8 bv0, bv1;
    const bool col0 = (row == 0);
    #pragma unroll
    for (int j = 0; j < 8; ++j) {
        bv0[j] = (short)f2bf(col0 ? w2v[kg * 8 + j] : 0.f);
        bv1[j] = (short)f2bf(col0 ? w2v[32 + kg * 8 + j] : 0.f);
    }

    f32x4 acc = {};
    #pragma unroll
    for (int h = 0; h < 2; ++h) {
        const int cb = 32 * h + kg * 8;
        short8 qv = *(const short8*)(pqr + (size_t)src * 256 + 64 + cb);
        short8 pv = *(const short8*)(pqr + (size_t)dst * 256 + cb);
        float4 bA = *(const float4*)(b1v + cb);
        float4 bB = *(const float4*)(b1v + cb + 4);
        short8 av;
        #pragma unroll
        for (int j = 0; j < 8; ++j) {
            float bb = (j < 4) ? ((const float*)&bA)[j] : ((const float*)&bB)[j - 4];
            float t = bf2f((ushort)qv[j]) + bf2f((ushort)pv[j]) + bb;
            av[j] = (short)f2bf_rn(fmaxf(t, 0.f));
        }
        acc = __builtin_amdgcn_mfma_f32_16x16x32_bf16(av, h ? bv1 : bv0, acc, 0, 0, 0);
    }
    // C col0 lives in lanes with row==0: lane kg*16 holds edges kg*4+j.
    if (row == 0) {
        float4 o;
        #pragma unroll
        for (int j = 0; j < 4; ++j) {
            float s = acc[j] + b2;
            ((float*)&o)[j] = 1.f / (1.f + __expf(-s));
        }
        *(float4*)(attv + e0 + kg * 4) = o;
    }
}

// ---- K_msg: per-dst weighted aggregation + bias + LN + ReLU + residual ----
// No shfl/expf in the edge loop; edge-attr term factored to 2 scalars/node.
// 3-stage pipeline: meta 2-ahead, r-gather 1-ahead.

__global__ __launch_bounds__(256) void k_msg(
    const int* __restrict__ offs, const uint2* __restrict__ adj,
    const float* __restrict__ attv, const ushort* __restrict__ pqr,
    const float* __restrict__ xin, const float* __restrict__ web,
    const float* __restrict__ biasv, const float* __restrict__ gammav,
    const float* __restrict__ betav, float* __restrict__ xout, int do_relu) {
    const int lane = threadIdx.x & 63;
    const int n = blockIdx.x * 4 + (threadIdx.x >> 6);
    const int c0 = 2 * lane;
    const float web00 = web[c0], web01 = web[c0 + 1];
    const float web10 = web[128 + c0], web11 = web[128 + c0 + 1];

    const int eb = offs[n], ee = offs[n + 1];
    const int cnt = ee - eb;
    float acc0 = 0.f, acc1 = 0.f, s0 = 0.f, s1 = 0.f;
    if (cnt > 0) {
        const int i1 = eb + (cnt > 1 ? 1 : 0);
        uint2 mA = adj[eb];  float aA = attv[eb];
        uint2 mB = adj[i1];  float aB = attv[i1];
        uint rA = *(const uint*)(pqr + (size_t)mA.x * 256 + 128 + c0);
        for (int i = 0; i < cnt; ++i) {
            const int i2 = (i + 2 < cnt) ? (eb + i + 2) : (ee - 1);
            uint2 mC = adj[i2];
            float aC = attv[i2];
            uint rB = *(const uint*)(pqr + (size_t)mB.x * 256 + 128 + c0);
            acc0 = fmaf(aA, bf2f((ushort)(rA & 0xffffu)), acc0);
            acc1 = fmaf(aA, bf2f((ushort)(rA >> 16)), acc1);
            s0 = fmaf(aA, bf2f((ushort)(mA.y & 0xffffu)), s0);
            s1 = fmaf(aA, bf2f((ushort)(mA.y >> 16)), s1);
            mA = mB; aA = aB; rA = rB;
            mB = mC; aB = aC;
        }
        acc0 += s0 * web00 + s1 * web10;
        acc1 += s0 * web01 + s1 * web11;
    }

    float v0 = acc0 + biasv[c0];
    float v1 = acc1 + biasv[c0 + 1];
    float sm = v0 + v1, sq = v0 * v0 + v1 * v1;
    #pragma unroll
    for (int o = 32; o > 0; o >>= 1) {
        sm += __shfl_xor(sm, o);
        sq += __shfl_xor(sq, o);
    }
    const float mean = sm * (1.f / 128.f);
    const float var = sq * (1.f / 128.f) - mean * mean;
    const float inv = rsqrtf(var + 1e-5f);
    float y0 = (v0 - mean) * inv * gammav[c0] + betav[c0];
    float y1 = (v1 - mean) * inv * gammav[c0 + 1] + betav[c0 + 1];
    if (do_relu) { y0 = fmaxf(y0, 0.f); y1 = fmaxf(y1, 0.f); }
    const float2 xr = *(const float2*)(xin + n * 128 + c0);
    y0 += xr.x;
    y1 += xr.y;
    float2 o2; o2.x = y0; o2.y = y1;
    *(float2*)(xout + n * 128 + c0) = o2;
}

// ---------------------------------------------------------------------------

extern "C" void kernel_launch(void* const* d_in, const int* in_sizes, int n_in,
                              void* d_out, int out_size, void* d_ws, size_t ws_size,
                              hipStream_t stream) {
    const float* x   = (const float*)d_in[0];
    const int*   ei  = (const int*)d_in[1];
    const float* ea  = (const float*)d_in[2];
    const float* wn  = (const float*)d_in[3];
    const float* wle = (const float*)d_in[4];
    const float* aw1 = (const float*)d_in[5];
    const float* ab1 = (const float*)d_in[6];
    const float* aw2 = (const float*)d_in[7];
    const float* ab2 = (const float*)d_in[8];
    const float* bia = (const float*)d_in[9];
    const float* gam = (const float*)d_in[10];
    const float* bet = (const float*)d_in[11];

    char* w = (char*)d_ws;
    size_t o = 0;
    auto alloc = [&](size_t bytes) {
        char* p = w + o;
        o = (o + bytes + 255) & ~(size_t)255;
        return p;
    };
    int*    counts = (int*)alloc((size_t)NN * 4);
    int*    offs   = (int*)alloc((size_t)(NN + 1) * 4);
    int*    cursor = (int*)alloc((size_t)NN * 4);
    int*    bsum   = (int*)alloc((size_t)NB * 4);
    int*    boff   = (int*)alloc((size_t)NB * 4);
    uint2*  adj    = (uint2*)alloc((size_t)EE * 8);
    uint*   adst   = (uint*)alloc((size_t)EE * 4);
    float*  attv   = (float*)alloc((size_t)EE * 4);
    ushort* wcT    = (ushort*)alloc((size_t)3 * 256 * 128 * 2);
    ushort* pqr    = (ushort*)alloc((size_t)NN * 256 * 2);
    float*  xb1    = (float*)alloc((size_t)NN * 128 * 4);
    float*  xb2    = (float*)alloc((size_t)NN * 128 * 4);

    hipMemsetAsync(counts, 0, (size_t)NN * 4, stream);
    k_hist<<<(EE + 255) / 256, 256, 0, stream>>>(ei, counts);
    k_scan_a<<<NB, 256, 0, stream>>>(counts, bsum);
    k_scan_b<<<1, 256, 0, stream>>>(bsum, boff, offs);
    k_scan_c<<<NB, 256, 0, stream>>>(counts, boff, offs, cursor);
    k_scatter<<<(EE + 255) / 256, 256, 0, stream>>>(ei, ea, cursor, adj, adst);
    k_compose<<<384, 256, 0, stream>>>(wn, aw1, wle, wcT);

    const float* xi = x;
    float* xo = xb1;
    for (int l = 0; l < 3; ++l) {
        k1_gemm<<<NN / 16, 256, 0, stream>>>(xi, wcT + (size_t)l * 256 * 128, pqr);
        k_att<<<EE / 64, 256, 0, stream>>>(adj, adst, pqr,
                                           ab1 + l * 64, aw2 + l * 64, ab2 + l, attv);
        const bool last = (l == 2);
        float* out_ptr = last ? (float*)d_out : xo;
        k_msg<<<NN / 4, 256, 0, stream>>>(
            offs, adj, attv, pqr, xi,
            wle + ((size_t)l * 130 + 128) * 128,
            bia + l * 128, gam + l * 128, bet + l * 128,
            out_ptr, last ? 0 : 1);
        xi = out_ptr;
        xo = (l == 0) ? xb2 : xb1;
    }
}